// Round 12
// baseline (1112.310 us; speedup 1.0000x reference)
//
#include <hip/hip_runtime.h>
#include <hip/hip_bf16.h>
#include <math.h>

// Problem dims
#define VOCAB 50001
#define EDIM 256
#define HDIM 256          // per-direction hidden
#define GDIM 1024         // 4*HDIM gates
#define KTAG 9
#define NB 64             // batch
#define NT 256            // time

// workspace layout (float offsets)
static constexpr size_t XP_OFF   = 0;                            // xproj [16384][2048]
static constexpr size_t HX_OFF   = XP_OFF + (size_t)16384*2048;  // u64 hx [2][256][128]
static constexpr size_t BIAS_OFF = HX_OFF + 131072;              // (unused, kept for layout)
static constexpr size_t HS_OFF   = BIAS_OFF + 2048;              // hstore [16384][512]
static constexpr size_t EM_OFF   = HS_OFF + (size_t)16384*512;   // emissions [16384][9]

#define FMA4(acc, W, H) acc += (W).x*(H).x + (W).y*(H).y + (W).z*(H).z + (W).w*(H).w

// ---------------------------------------------------------------------------
// xproj GEMM v3: 128x128 tile, 8x8 acc/thread, BK=16, single-barrier
// double-buffered LDS. Bias (b_ih+b_hh) applied inline in the epilogue.
// Block (0,0) additionally zeroes the hx exchange buffer (replay-safe;
// kernel completes before k_rec3 launches). Grid 128x16 = 2048 blocks.
#define XBK 16
#define FMARC(I, AX) \
    acc[I][0] += (AX)*b0.x; acc[I][1] += (AX)*b0.y; acc[I][2] += (AX)*b0.z; acc[I][3] += (AX)*b0.w; \
    acc[I][4] += (AX)*b1.x; acc[I][5] += (AX)*b1.y; acc[I][6] += (AX)*b1.z; acc[I][7] += (AX)*b1.w;

__global__ __launch_bounds__(256) void k_xproj(const int* __restrict__ x,
                                               const float* __restrict__ embed,
                                               const float* __restrict__ wih_f,
                                               const float* __restrict__ wih_b,
                                               const float* __restrict__ bif,
                                               const float* __restrict__ bhf,
                                               const float* __restrict__ bib,
                                               const float* __restrict__ bhb,
                                               float* __restrict__ ws) {
    float* xp = ws + XP_OFF;
    __shared__ float As[2][XBK][132];   // [buf][k][m], +4 pad
    __shared__ float Bs[2][XBK][132];
    __shared__ int ids[128];
    const int bm = blockIdx.x;       // 0..127
    const int bn = blockIdx.y;       // 0..15
    const int tid = threadIdx.x;
    const int tx = tid & 15, ty = tid >> 4;

    // block (0,0): zero hx (64K u64) alongside its GEMM work
    if (bm == 0 && bn == 0) {
        unsigned long long* hx = (unsigned long long*)(ws + HX_OFF);
        for (int i = tid; i < 65536; i += 256) hx[i] = 0ull;
    }

    if (tid < 128) {
        int r = bm * 128 + tid;
        int t = r >> 6, b = r & 63;
        ids[tid] = x[b * 256 + t];
    }
    __syncthreads();

    float acc[8][8];
#pragma unroll
    for (int i = 0; i < 8; ++i)
#pragma unroll
        for (int j = 0; j < 8; ++j) acc[i][j] = 0.f;

    const int lrow = tid >> 1;          // 0..127
    const int lseg = (tid & 1) * 8;     // 0 or 8
    const int gnb = bn * 128 + lrow;
    const float* wsrc = (gnb < 1024) ? (wih_f + (size_t)gnb * 256)
                                     : (wih_b + (size_t)(gnb - 1024) * 256);
    const float* asrc = embed + (size_t)ids[lrow] * 256;

    // prologue: load tile 0 into buf 0
    {
        float4 a0 = *reinterpret_cast<const float4*>(asrc + lseg);
        float4 a1 = *reinterpret_cast<const float4*>(asrc + lseg + 4);
        float4 b0 = *reinterpret_cast<const float4*>(wsrc + lseg);
        float4 b1 = *reinterpret_cast<const float4*>(wsrc + lseg + 4);
        As[0][lseg + 0][lrow] = a0.x; As[0][lseg + 1][lrow] = a0.y;
        As[0][lseg + 2][lrow] = a0.z; As[0][lseg + 3][lrow] = a0.w;
        As[0][lseg + 4][lrow] = a1.x; As[0][lseg + 5][lrow] = a1.y;
        As[0][lseg + 6][lrow] = a1.z; As[0][lseg + 7][lrow] = a1.w;
        Bs[0][lseg + 0][lrow] = b0.x; Bs[0][lseg + 1][lrow] = b0.y;
        Bs[0][lseg + 2][lrow] = b0.z; Bs[0][lseg + 3][lrow] = b0.w;
        Bs[0][lseg + 4][lrow] = b1.x; Bs[0][lseg + 5][lrow] = b1.y;
        Bs[0][lseg + 6][lrow] = b1.z; Bs[0][lseg + 7][lrow] = b1.w;
    }
    __syncthreads();

    for (int kt = 0; kt < 16; ++kt) {
        const int cur = kt & 1;
        float4 na0, na1, nb0, nb1;
        if (kt < 15) {   // issue next-tile loads early (latency hides under FMAs)
            const int k0 = (kt + 1) * XBK;
            na0 = *reinterpret_cast<const float4*>(asrc + k0 + lseg);
            na1 = *reinterpret_cast<const float4*>(asrc + k0 + lseg + 4);
            nb0 = *reinterpret_cast<const float4*>(wsrc + k0 + lseg);
            nb1 = *reinterpret_cast<const float4*>(wsrc + k0 + lseg + 4);
        }
#pragma unroll
        for (int kk = 0; kk < XBK; ++kk) {
            float4 a0 = *reinterpret_cast<const float4*>(&As[cur][kk][ty * 8]);
            float4 a1 = *reinterpret_cast<const float4*>(&As[cur][kk][ty * 8 + 4]);
            float4 b0 = *reinterpret_cast<const float4*>(&Bs[cur][kk][tx * 8]);
            float4 b1 = *reinterpret_cast<const float4*>(&Bs[cur][kk][tx * 8 + 4]);
            FMARC(0, a0.x) FMARC(1, a0.y) FMARC(2, a0.z) FMARC(3, a0.w)
            FMARC(4, a1.x) FMARC(5, a1.y) FMARC(6, a1.z) FMARC(7, a1.w)
        }
        if (kt < 15) {
            const int nxt = cur ^ 1;
            // writes go to the buffer everyone finished computing last iter;
            // safe concurrent with compute of buf[cur]; one barrier suffices.
            As[nxt][lseg + 0][lrow] = na0.x; As[nxt][lseg + 1][lrow] = na0.y;
            As[nxt][lseg + 2][lrow] = na0.z; As[nxt][lseg + 3][lrow] = na0.w;
            As[nxt][lseg + 4][lrow] = na1.x; As[nxt][lseg + 5][lrow] = na1.y;
            As[nxt][lseg + 6][lrow] = na1.z; As[nxt][lseg + 7][lrow] = na1.w;
            Bs[nxt][lseg + 0][lrow] = nb0.x; Bs[nxt][lseg + 1][lrow] = nb0.y;
            Bs[nxt][lseg + 2][lrow] = nb0.z; Bs[nxt][lseg + 3][lrow] = nb0.w;
            Bs[nxt][lseg + 4][lrow] = nb1.x; Bs[nxt][lseg + 5][lrow] = nb1.y;
            Bs[nxt][lseg + 6][lrow] = nb1.z; Bs[nxt][lseg + 7][lrow] = nb1.w;
            __syncthreads();
        }
    }

    const int gm = bm * 128 + ty * 8;
    const int gn = bn * 128 + tx * 8;
    // inline bias: b_ih + b_hh for this thread's 8 output columns
    float bias8[8];
#pragma unroll
    for (int j = 0; j < 8; ++j) {
        const int g = gn + j;
        bias8[j] = (g < 1024) ? (bif[g] + bhf[g]) : (bib[g - 1024] + bhb[g - 1024]);
    }
#pragma unroll
    for (int i = 0; i < 8; ++i) {
        float4 o0, o1;
        o0.x = acc[i][0] + bias8[0]; o0.y = acc[i][1] + bias8[1];
        o0.z = acc[i][2] + bias8[2]; o0.w = acc[i][3] + bias8[3];
        o1.x = acc[i][4] + bias8[4]; o1.y = acc[i][5] + bias8[5];
        o1.z = acc[i][6] + bias8[6]; o1.w = acc[i][7] + bias8[7];
        *reinterpret_cast<float4*>(xp + (size_t)(gm + i) * 2048 + gn) = o0;
        *reinterpret_cast<float4*>(xp + (size_t)(gm + i) * 2048 + gn + 4) = o1;
    }
}

// ---------------------------------------------------------------------------
// Recurrence v3b (EXACT round-8 proven kernel, 677 us, absmax 0): 3 barriers,
// t<128 spin, partner ^128, parity u64 hx; h via wave-uniform LDS broadcast.
#define WV 23
#define WL 9
#define REC_LDS_FLOATS (WL * 1024 * 4 + 256 + 512 + 512)   // 38,144 f = 152,576 B

__global__ __launch_bounds__(1024)
__attribute__((amdgpu_waves_per_eu(4, 4)))
void k_rec3(const float* __restrict__ whh_f,
            const float* __restrict__ whh_b,
            float* __restrict__ ws) {
    extern __shared__ float sm[];
    float4* wlds4 = reinterpret_cast<float4*>(sm);   // [WL][1024]
    float* hbuf = sm + WL * 1024 * 4;                // [256]
    float* gact = hbuf + 256;                        // [512]
    float* psum = gact + 512;                        // [512]

    const float* xp = ws + XP_OFF;
    unsigned long long* hx = (unsigned long long*)(ws + HX_OFF);
    float* hs = ws + HS_OFF;

    const int blk = blockIdx.x;
    const int jhalf = blk >> 7;
    const int dir = (blk >> 6) & 1;
    const int batch = blk & 63;
    const int partner = blk ^ 128;
    const int t = threadIdx.x;
    const int kh = t >> 9;                  // k-half of the row (wave-uniform)
    const int rr = t & 511;                 // row within block
    const int gt = rr >> 7;                 // gate 0:i 1:f 2:g 3:o
    const int jj = rr & 127;
    const int row_global = gt * 256 + jhalf * 128 + jj;
    const int col = dir * 1024 + row_global;
    const float* wrow = (dir ? whh_b : whh_f) + (size_t)row_global * 256 + kh * 128;

    // preload weights: 92 floats -> VGPR/AGPR, 36 floats -> LDS (per thread)
    float4 w4[WV];
#pragma unroll
    for (int i = 0; i < WV; ++i) w4[i] = reinterpret_cast<const float4*>(wrow)[i];
#pragma unroll
    for (int c = 0; c < WL; ++c)
        wlds4[c * 1024 + t] = reinterpret_cast<const float4*>(wrow)[WV + c];

    if (t < 256) hbuf[t] = 0.f;
    float creg = 0.f;
    __syncthreads();

    const long xstep = dir ? -131072 : 131072;       // floats per time step
    const long hstep = dir ? -32768 : 32768;
    const float* xptr = xp + (size_t)(dir ? 255 : 0) * 131072 + (size_t)batch * 2048 + col;
    float* hsptr = hs + (size_t)(dir ? 255 : 0) * 32768 + (size_t)batch * 512
                   + dir * 256 + jhalf * 128 + t;    // only t<128 dereferences
    float xpv = (t < 512) ? *xptr : 0.f;

    for (int s = 0; s < 256; ++s) {
        // h operand: wave-uniform broadcast reads from LDS (kh uniform/wave)
        const float* hk = hbuf + kh * 128;

        float a0 = 0.f, a1 = 0.f, a2 = 0.f, a3 = 0.f;
#pragma unroll
        for (int q = 0; q < WV; q += 4) {
            float4 h4;
            h4 = *reinterpret_cast<const float4*>(hk + (q + 0) * 4);
            FMA4(a0, w4[q + 0], h4);
            if (q + 1 < WV) { h4 = *reinterpret_cast<const float4*>(hk + (q + 1) * 4); FMA4(a1, w4[q + 1], h4); }
            if (q + 2 < WV) { h4 = *reinterpret_cast<const float4*>(hk + (q + 2) * 4); FMA4(a2, w4[q + 2], h4); }
            if (q + 3 < WV) { h4 = *reinterpret_cast<const float4*>(hk + (q + 3) * 4); FMA4(a3, w4[q + 3], h4); }
        }
#pragma unroll
        for (int c = 0; c < WL; ++c) {
            float4 h4 = *reinterpret_cast<const float4*>(hk + (WV + c) * 4);
            float4 wl = wlds4[c * 1024 + t];
            if ((c & 3) == 0) FMA4(a0, wl, h4);
            else if ((c & 3) == 1) FMA4(a1, wl, h4);
            else if ((c & 3) == 2) FMA4(a2, wl, h4);
            else FMA4(a3, wl, h4);
        }
        const float a = (a0 + a1) + (a2 + a3);

        if (kh) psum[rr] = a;
        __syncthreads();

        if (t < 512) {   // waves 0..7, gt wave-uniform
            const float acc = xpv + a + psum[t];
            const float act = (gt == 2) ? tanhf(acc) : 1.f / (1.f + expf(-acc));
            gact[t] = act;
        }
        __syncthreads();

        if (t < 128) {   // waves 0,1
            const float si = gact[t], sf = gact[128 + t], tg = gact[256 + t], so = gact[384 + t];
            creg = sf * creg + si * tg;
            const float hval = so * tanhf(creg);
            const unsigned long long pk =
                ((unsigned long long)(unsigned)(s + 1) << 32) | (unsigned)__float_as_uint(hval);
            __hip_atomic_store(&hx[((size_t)(s & 1) * 256 + blk) * 128 + t], pk,
                               __ATOMIC_RELAXED, __HIP_MEMORY_SCOPE_AGENT);
            hbuf[jhalf * 128 + t] = hval;
            *hsptr = hval;
            hsptr += hstep;
        }

        if (t < 512 && s < 255) { xptr += xstep; xpv = *xptr; }

        if (t < 128) {
            unsigned long long u;
            do {
                u = __hip_atomic_load(&hx[((size_t)(s & 1) * 256 + partner) * 128 + t],
                                      __ATOMIC_RELAXED, __HIP_MEMORY_SCOPE_AGENT);
            } while ((unsigned)(u >> 32) != (unsigned)(s + 1));
            hbuf[(1 - jhalf) * 128 + t] = __uint_as_float((unsigned)u);
        }
        __syncthreads();
    }
}

// ---------------------------------------------------------------------------
// Emissions: em[r][j] = dot(hstore[r][0:512], w_out[j]) + b_out[j]
__global__ __launch_bounds__(256) void k_emis(const float* __restrict__ wout,
                                              const float* __restrict__ bout,
                                              float* __restrict__ ws) {
    const float* hs = ws + HS_OFF;
    float* em = ws + EM_OFF;
    __shared__ float wl[9][512];
    __shared__ float bl[9];
    const int tid = threadIdx.x;
    for (int i = tid; i < 9 * 512; i += 256) wl[i / 512][i % 512] = wout[i];
    if (tid < 9) bl[tid] = bout[tid];
    __syncthreads();

    const int r = blockIdx.x * 256 + tid;
    const float4* hrow = reinterpret_cast<const float4*>(hs + (size_t)r * 512);
    float acc[9];
#pragma unroll
    for (int j = 0; j < 9; ++j) acc[j] = bl[j];
    for (int k4 = 0; k4 < 128; ++k4) {
        float4 h = hrow[k4];
#pragma unroll
        for (int j = 0; j < 9; ++j) {
            float4 w = *reinterpret_cast<const float4*>(&wl[j][k4 * 4]);
            acc[j] += h.x * w.x + h.y * w.y + h.z * w.z + h.w * w.w;
        }
    }
#pragma unroll
    for (int j = 0; j < 9; ++j) em[(size_t)r * 9 + j] = acc[j];
}

// ---------------------------------------------------------------------------
// Viterbi: one block per batch; strict-> first-index argmax matches jnp.
__global__ __launch_bounds__(64) void k_vit(const float* __restrict__ start,
                                            const float* __restrict__ endv,
                                            const float* __restrict__ trans,
                                            const float* __restrict__ ws_c,
                                            float* __restrict__ out) {
    const float* em = ws_c + EM_OFF;
    const int b = blockIdx.x;
    const int lane = threadIdx.x;
    __shared__ float tr[81];
    __shared__ float sc[9];
    __shared__ float ns[9];
    __shared__ int hist[256][9];

    for (int i = lane; i < 81; i += 64) tr[i] = trans[i];
    if (lane < 9) sc[lane] = start[lane] + em[(size_t)b * 9 + lane];
    __syncthreads();

    for (int t = 1; t < 256; ++t) {
        if (lane < 9) {
            float e = em[((size_t)t * 64 + b) * 9 + lane];
            float best = -1e30f; int bi = 0;
#pragma unroll
            for (int i = 0; i < 9; ++i) {
                float v = sc[i] + tr[i * 9 + lane];
                if (v > best) { best = v; bi = i; }
            }
            ns[lane] = best + e;
            hist[t][lane] = bi;
        }
        __syncthreads();
        if (lane < 9) sc[lane] = ns[lane];
        __syncthreads();
    }

    if (lane == 0) {
        float best = -1e30f; int bi = 0;
        for (int j = 0; j < 9; ++j) {
            float v = sc[j] + endv[j];
            if (v > best) { best = v; bi = j; }
        }
        out[16384 + b] = best;
        int cur = bi;
        out[(size_t)b * 256 + 255] = (float)cur;
        for (int t = 255; t >= 1; --t) {
            cur = hist[t][cur];
            out[(size_t)b * 256 + t - 1] = (float)cur;
        }
    }
}

// ---------------------------------------------------------------------------
extern "C" void kernel_launch(void* const* d_in, const int* in_sizes, int n_in,
                              void* d_out, int out_size, void* d_ws, size_t ws_size,
                              hipStream_t stream) {
    (void)in_sizes; (void)n_in; (void)out_size; (void)ws_size;
    const int*   x       = (const int*)d_in[0];
    const float* embed   = (const float*)d_in[1];
    const float* w_ih_f  = (const float*)d_in[2];
    const float* w_hh_f  = (const float*)d_in[3];
    const float* b_ih_f  = (const float*)d_in[4];
    const float* b_hh_f  = (const float*)d_in[5];
    const float* w_ih_b  = (const float*)d_in[6];
    const float* w_hh_b  = (const float*)d_in[7];
    const float* b_ih_b  = (const float*)d_in[8];
    const float* b_hh_b  = (const float*)d_in[9];
    const float* w_out   = (const float*)d_in[10];
    const float* b_out   = (const float*)d_in[11];
    const float* crf_start = (const float*)d_in[12];
    const float* crf_end   = (const float*)d_in[13];
    const float* crf_trans = (const float*)d_in[14];
    float* ws  = (float*)d_ws;
    float* out = (float*)d_out;

    const size_t rec_lds_bytes = (size_t)REC_LDS_FLOATS * 4;   // 152,576 B
    hipFuncSetAttribute(reinterpret_cast<const void*>(k_rec3),
                        hipFuncAttributeMaxDynamicSharedMemorySize,
                        (int)rec_lds_bytes);

    hipLaunchKernelGGL(k_xproj, dim3(128, 16), dim3(256), 0, stream,
                       x, embed, w_ih_f, w_ih_b,
                       b_ih_f, b_hh_f, b_ih_b, b_hh_b, ws);
    hipLaunchKernelGGL(k_rec3, dim3(256), dim3(1024), rec_lds_bytes, stream,
                       w_hh_f, w_hh_b, ws);
    hipLaunchKernelGGL(k_emis, dim3(64), dim3(256), 0, stream, w_out, b_out, ws);
    hipLaunchKernelGGL(k_vit, dim3(64), dim3(64), 0, stream,
                       crf_start, crf_end, crf_trans, ws, out);
}

// Round 13
// 969.279 us; speedup vs baseline: 1.1476x; 1.1476x over previous
//
#include <hip/hip_runtime.h>
#include <hip/hip_bf16.h>
#include <math.h>

// Problem dims
#define VOCAB 50001
#define EDIM 256
#define HDIM 256          // per-direction hidden
#define GDIM 1024         // 4*HDIM gates
#define KTAG 9
#define NB 64             // batch
#define NT 256            // time

// workspace layout (float offsets)
static constexpr size_t XP_OFF   = 0;                            // xproj [16384][2048]
static constexpr size_t HX_OFF   = XP_OFF + (size_t)16384*2048;  // u64 hx [2][256][128]
static constexpr size_t BIAS_OFF = HX_OFF + 131072;              // [2048]
static constexpr size_t HS_OFF   = BIAS_OFF + 2048;              // hstore [16384][512]
static constexpr size_t EM_OFF   = HS_OFF + (size_t)16384*512;   // emissions [16384][9]

#define FMA4(acc, W, H) acc += (W).x*(H).x + (W).y*(H).y + (W).z*(H).z + (W).w*(H).w

// ---------------------------------------------------------------------------
// Prep: combined bias, zero the tagged h-exchange buffer (replay-safe).
__global__ __launch_bounds__(256) void k_prep(const float* __restrict__ bif,
                                              const float* __restrict__ bhf,
                                              const float* __restrict__ bib,
                                              const float* __restrict__ bhb,
                                              float* __restrict__ ws) {
    int t = blockIdx.x * 256 + threadIdx.x;   // grid 16x256 = 4096
    float* bias = ws + BIAS_OFF;
    if (t < 2048) {
        int d = t >> 10, g = t & 1023;
        bias[t] = d ? (bib[g] + bhb[g]) : (bif[g] + bhf[g]);
    }
    unsigned long long* hx = (unsigned long long*)(ws + HX_OFF);
    for (int i = t; i < 65536; i += 4096) hx[i] = 0ull;
}

// ---------------------------------------------------------------------------
// xproj GEMM v2 (round-10 proven): 128x128 tile, 8x8 acc/thread, BK=16.
#define XBK 16
#define FMARC(I, AX) \
    acc[I][0] += (AX)*b0.x; acc[I][1] += (AX)*b0.y; acc[I][2] += (AX)*b0.z; acc[I][3] += (AX)*b0.w; \
    acc[I][4] += (AX)*b1.x; acc[I][5] += (AX)*b1.y; acc[I][6] += (AX)*b1.z; acc[I][7] += (AX)*b1.w;

__global__ __launch_bounds__(256) void k_xproj(const int* __restrict__ x,
                                               const float* __restrict__ embed,
                                               const float* __restrict__ wih_f,
                                               const float* __restrict__ wih_b,
                                               float* __restrict__ ws) {
    float* xp = ws + XP_OFF;
    const float* bias = ws + BIAS_OFF;
    __shared__ float As[XBK][132];   // [k][m], +4 pad
    __shared__ float Bs[XBK][132];   // [k][n]
    __shared__ int ids[128];
    const int bm = blockIdx.x;       // 0..127
    const int bn = blockIdx.y;       // 0..15
    const int tid = threadIdx.x;
    const int tx = tid & 15, ty = tid >> 4;

    if (tid < 128) {
        int r = bm * 128 + tid;
        int t = r >> 6, b = r & 63;
        ids[tid] = x[b * 256 + t];
    }
    __syncthreads();

    float acc[8][8];
#pragma unroll
    for (int i = 0; i < 8; ++i)
#pragma unroll
        for (int j = 0; j < 8; ++j) acc[i][j] = 0.f;

    const int lrow = tid >> 1;          // 0..127
    const int lseg = (tid & 1) * 8;     // 0 or 8
    const int gnb = bn * 128 + lrow;
    const float* wsrc = (gnb < 1024) ? (wih_f + (size_t)gnb * 256)
                                     : (wih_b + (size_t)(gnb - 1024) * 256);
    const float* asrc = embed + (size_t)ids[lrow] * 256;

    for (int k0 = 0; k0 < 256; k0 += XBK) {
        {
            const float* src = asrc + k0 + lseg;
            float4 a0 = *reinterpret_cast<const float4*>(src);
            float4 a1 = *reinterpret_cast<const float4*>(src + 4);
            As[lseg + 0][lrow] = a0.x; As[lseg + 1][lrow] = a0.y;
            As[lseg + 2][lrow] = a0.z; As[lseg + 3][lrow] = a0.w;
            As[lseg + 4][lrow] = a1.x; As[lseg + 5][lrow] = a1.y;
            As[lseg + 6][lrow] = a1.z; As[lseg + 7][lrow] = a1.w;
        }
        {
            const float* src = wsrc + k0 + lseg;
            float4 b0 = *reinterpret_cast<const float4*>(src);
            float4 b1 = *reinterpret_cast<const float4*>(src + 4);
            Bs[lseg + 0][lrow] = b0.x; Bs[lseg + 1][lrow] = b0.y;
            Bs[lseg + 2][lrow] = b0.z; Bs[lseg + 3][lrow] = b0.w;
            Bs[lseg + 4][lrow] = b1.x; Bs[lseg + 5][lrow] = b1.y;
            Bs[lseg + 6][lrow] = b1.z; Bs[lseg + 7][lrow] = b1.w;
        }
        __syncthreads();
#pragma unroll
        for (int kk = 0; kk < XBK; ++kk) {
            float4 a0 = *reinterpret_cast<const float4*>(&As[kk][ty * 8]);
            float4 a1 = *reinterpret_cast<const float4*>(&As[kk][ty * 8 + 4]);
            float4 b0 = *reinterpret_cast<const float4*>(&Bs[kk][tx * 8]);
            float4 b1 = *reinterpret_cast<const float4*>(&Bs[kk][tx * 8 + 4]);
            FMARC(0, a0.x) FMARC(1, a0.y) FMARC(2, a0.z) FMARC(3, a0.w)
            FMARC(4, a1.x) FMARC(5, a1.y) FMARC(6, a1.z) FMARC(7, a1.w)
        }
        __syncthreads();
    }

    const int gm = bm * 128 + ty * 8;
    const int gn = bn * 128 + tx * 8;
    float4 bi0, bi1;
    bi0.x = bias[gn + 0]; bi0.y = bias[gn + 1]; bi0.z = bias[gn + 2]; bi0.w = bias[gn + 3];
    bi1.x = bias[gn + 4]; bi1.y = bias[gn + 5]; bi1.z = bias[gn + 6]; bi1.w = bias[gn + 7];
#pragma unroll
    for (int i = 0; i < 8; ++i) {
        float4 o0, o1;
        o0.x = acc[i][0] + bi0.x; o0.y = acc[i][1] + bi0.y;
        o0.z = acc[i][2] + bi0.z; o0.w = acc[i][3] + bi0.w;
        o1.x = acc[i][4] + bi1.x; o1.y = acc[i][5] + bi1.y;
        o1.z = acc[i][6] + bi1.z; o1.w = acc[i][7] + bi1.w;
        *reinterpret_cast<float4*>(xp + (size_t)(gm + i) * 2048 + gn) = o0;
        *reinterpret_cast<float4*>(xp + (size_t)(gm + i) * 2048 + gn + 4) = o1;
    }
}

// ---------------------------------------------------------------------------
// Recurrence v3b (EXACT round-8 proven kernel, 677 us, absmax 0): 3 barriers,
// t<128 spin, partner ^128, parity u64 hx; h via wave-uniform LDS broadcast.
#define WV 23
#define WL 9
#define REC_LDS_FLOATS (WL * 1024 * 4 + 256 + 512 + 512)   // 38,144 f = 152,576 B

__global__ __launch_bounds__(1024)
__attribute__((amdgpu_waves_per_eu(4, 4)))
void k_rec3(const float* __restrict__ whh_f,
            const float* __restrict__ whh_b,
            float* __restrict__ ws) {
    extern __shared__ float sm[];
    float4* wlds4 = reinterpret_cast<float4*>(sm);   // [WL][1024]
    float* hbuf = sm + WL * 1024 * 4;                // [256]
    float* gact = hbuf + 256;                        // [512]
    float* psum = gact + 512;                        // [512]

    const float* xp = ws + XP_OFF;
    unsigned long long* hx = (unsigned long long*)(ws + HX_OFF);
    float* hs = ws + HS_OFF;

    const int blk = blockIdx.x;
    const int jhalf = blk >> 7;
    const int dir = (blk >> 6) & 1;
    const int batch = blk & 63;
    const int partner = blk ^ 128;
    const int t = threadIdx.x;
    const int kh = t >> 9;                  // k-half of the row (wave-uniform)
    const int rr = t & 511;                 // row within block
    const int gt = rr >> 7;                 // gate 0:i 1:f 2:g 3:o
    const int jj = rr & 127;
    const int row_global = gt * 256 + jhalf * 128 + jj;
    const int col = dir * 1024 + row_global;
    const float* wrow = (dir ? whh_b : whh_f) + (size_t)row_global * 256 + kh * 128;

    // preload weights: 92 floats -> VGPR/AGPR, 36 floats -> LDS (per thread)
    float4 w4[WV];
#pragma unroll
    for (int i = 0; i < WV; ++i) w4[i] = reinterpret_cast<const float4*>(wrow)[i];
#pragma unroll
    for (int c = 0; c < WL; ++c)
        wlds4[c * 1024 + t] = reinterpret_cast<const float4*>(wrow)[WV + c];

    if (t < 256) hbuf[t] = 0.f;
    float creg = 0.f;
    __syncthreads();

    const long xstep = dir ? -131072 : 131072;       // floats per time step
    const long hstep = dir ? -32768 : 32768;
    const float* xptr = xp + (size_t)(dir ? 255 : 0) * 131072 + (size_t)batch * 2048 + col;
    float* hsptr = hs + (size_t)(dir ? 255 : 0) * 32768 + (size_t)batch * 512
                   + dir * 256 + jhalf * 128 + t;    // only t<128 dereferences
    float xpv = (t < 512) ? *xptr : 0.f;

    for (int s = 0; s < 256; ++s) {
        // h operand: wave-uniform broadcast reads from LDS (kh uniform/wave)
        const float* hk = hbuf + kh * 128;

        float a0 = 0.f, a1 = 0.f, a2 = 0.f, a3 = 0.f;
#pragma unroll
        for (int q = 0; q < WV; q += 4) {
            float4 h4;
            h4 = *reinterpret_cast<const float4*>(hk + (q + 0) * 4);
            FMA4(a0, w4[q + 0], h4);
            if (q + 1 < WV) { h4 = *reinterpret_cast<const float4*>(hk + (q + 1) * 4); FMA4(a1, w4[q + 1], h4); }
            if (q + 2 < WV) { h4 = *reinterpret_cast<const float4*>(hk + (q + 2) * 4); FMA4(a2, w4[q + 2], h4); }
            if (q + 3 < WV) { h4 = *reinterpret_cast<const float4*>(hk + (q + 3) * 4); FMA4(a3, w4[q + 3], h4); }
        }
#pragma unroll
        for (int c = 0; c < WL; ++c) {
            float4 h4 = *reinterpret_cast<const float4*>(hk + (WV + c) * 4);
            float4 wl = wlds4[c * 1024 + t];
            if ((c & 3) == 0) FMA4(a0, wl, h4);
            else if ((c & 3) == 1) FMA4(a1, wl, h4);
            else if ((c & 3) == 2) FMA4(a2, wl, h4);
            else FMA4(a3, wl, h4);
        }
        const float a = (a0 + a1) + (a2 + a3);

        if (kh) psum[rr] = a;
        __syncthreads();

        if (t < 512) {   // waves 0..7, gt wave-uniform
            const float acc = xpv + a + psum[t];
            const float act = (gt == 2) ? tanhf(acc) : 1.f / (1.f + expf(-acc));
            gact[t] = act;
        }
        __syncthreads();

        if (t < 128) {   // waves 0,1
            const float si = gact[t], sf = gact[128 + t], tg = gact[256 + t], so = gact[384 + t];
            creg = sf * creg + si * tg;
            const float hval = so * tanhf(creg);
            const unsigned long long pk =
                ((unsigned long long)(unsigned)(s + 1) << 32) | (unsigned)__float_as_uint(hval);
            __hip_atomic_store(&hx[((size_t)(s & 1) * 256 + blk) * 128 + t], pk,
                               __ATOMIC_RELAXED, __HIP_MEMORY_SCOPE_AGENT);
            hbuf[jhalf * 128 + t] = hval;
            *hsptr = hval;
            hsptr += hstep;
        }

        if (t < 512 && s < 255) { xptr += xstep; xpv = *xptr; }

        if (t < 128) {
            unsigned long long u;
            do {
                u = __hip_atomic_load(&hx[((size_t)(s & 1) * 256 + partner) * 128 + t],
                                      __ATOMIC_RELAXED, __HIP_MEMORY_SCOPE_AGENT);
            } while ((unsigned)(u >> 32) != (unsigned)(s + 1));
            hbuf[(1 - jhalf) * 128 + t] = __uint_as_float((unsigned)u);
        }
        __syncthreads();
    }
}

// ---------------------------------------------------------------------------
// Emissions: em[r][j] = dot(hstore[r][0:512], w_out[j]) + b_out[j]
__global__ __launch_bounds__(256) void k_emis(const float* __restrict__ wout,
                                              const float* __restrict__ bout,
                                              float* __restrict__ ws) {
    const float* hs = ws + HS_OFF;
    float* em = ws + EM_OFF;
    __shared__ float wl[9][512];
    __shared__ float bl[9];
    const int tid = threadIdx.x;
    for (int i = tid; i < 9 * 512; i += 256) wl[i / 512][i % 512] = wout[i];
    if (tid < 9) bl[tid] = bout[tid];
    __syncthreads();

    const int r = blockIdx.x * 256 + tid;
    const float4* hrow = reinterpret_cast<const float4*>(hs + (size_t)r * 512);
    float acc[9];
#pragma unroll
    for (int j = 0; j < 9; ++j) acc[j] = bl[j];
    for (int k4 = 0; k4 < 128; ++k4) {
        float4 h = hrow[k4];
#pragma unroll
        for (int j = 0; j < 9; ++j) {
            float4 w = *reinterpret_cast<const float4*>(&wl[j][k4 * 4]);
            acc[j] += h.x * w.x + h.y * w.y + h.z * w.z + h.w * w.w;
        }
    }
#pragma unroll
    for (int j = 0; j < 9; ++j) em[(size_t)r * 9 + j] = acc[j];
}

// ---------------------------------------------------------------------------
// Viterbi: one block per batch; strict-> first-index argmax matches jnp.
__global__ __launch_bounds__(64) void k_vit(const float* __restrict__ start,
                                            const float* __restrict__ endv,
                                            const float* __restrict__ trans,
                                            const float* __restrict__ ws_c,
                                            float* __restrict__ out) {
    const float* em = ws_c + EM_OFF;
    const int b = blockIdx.x;
    const int lane = threadIdx.x;
    __shared__ float tr[81];
    __shared__ float sc[9];
    __shared__ float ns[9];
    __shared__ int hist[256][9];

    for (int i = lane; i < 81; i += 64) tr[i] = trans[i];
    if (lane < 9) sc[lane] = start[lane] + em[(size_t)b * 9 + lane];
    __syncthreads();

    for (int t = 1; t < 256; ++t) {
        if (lane < 9) {
            float e = em[((size_t)t * 64 + b) * 9 + lane];
            float best = -1e30f; int bi = 0;
#pragma unroll
            for (int i = 0; i < 9; ++i) {
                float v = sc[i] + tr[i * 9 + lane];
                if (v > best) { best = v; bi = i; }
            }
            ns[lane] = best + e;
            hist[t][lane] = bi;
        }
        __syncthreads();
        if (lane < 9) sc[lane] = ns[lane];
        __syncthreads();
    }

    if (lane == 0) {
        float best = -1e30f; int bi = 0;
        for (int j = 0; j < 9; ++j) {
            float v = sc[j] + endv[j];
            if (v > best) { best = v; bi = j; }
        }
        out[16384 + b] = best;
        int cur = bi;
        out[(size_t)b * 256 + 255] = (float)cur;
        for (int t = 255; t >= 1; --t) {
            cur = hist[t][cur];
            out[(size_t)b * 256 + t - 1] = (float)cur;
        }
    }
}

// ---------------------------------------------------------------------------
extern "C" void kernel_launch(void* const* d_in, const int* in_sizes, int n_in,
                              void* d_out, int out_size, void* d_ws, size_t ws_size,
                              hipStream_t stream) {
    (void)in_sizes; (void)n_in; (void)out_size; (void)ws_size;
    const int*   x       = (const int*)d_in[0];
    const float* embed   = (const float*)d_in[1];
    const float* w_ih_f  = (const float*)d_in[2];
    const float* w_hh_f  = (const float*)d_in[3];
    const float* b_ih_f  = (const float*)d_in[4];
    const float* b_hh_f  = (const float*)d_in[5];
    const float* w_ih_b  = (const float*)d_in[6];
    const float* w_hh_b  = (const float*)d_in[7];
    const float* b_ih_b  = (const float*)d_in[8];
    const float* b_hh_b  = (const float*)d_in[9];
    const float* w_out   = (const float*)d_in[10];
    const float* b_out   = (const float*)d_in[11];
    const float* crf_start = (const float*)d_in[12];
    const float* crf_end   = (const float*)d_in[13];
    const float* crf_trans = (const float*)d_in[14];
    float* ws  = (float*)d_ws;
    float* out = (float*)d_out;

    const size_t rec_lds_bytes = (size_t)REC_LDS_FLOATS * 4;   // 152,576 B
    hipFuncSetAttribute(reinterpret_cast<const void*>(k_rec3),
                        hipFuncAttributeMaxDynamicSharedMemorySize,
                        (int)rec_lds_bytes);

    hipLaunchKernelGGL(k_prep, dim3(16), dim3(256), 0, stream,
                       b_ih_f, b_hh_f, b_ih_b, b_hh_b, ws);
    hipLaunchKernelGGL(k_xproj, dim3(128, 16), dim3(256), 0, stream,
                       x, embed, w_ih_f, w_ih_b, ws);
    hipLaunchKernelGGL(k_rec3, dim3(256), dim3(1024), rec_lds_bytes, stream,
                       w_hh_f, w_hh_b, ws);
    hipLaunchKernelGGL(k_emis, dim3(64), dim3(256), 0, stream, w_out, b_out, ws);
    hipLaunchKernelGGL(k_vit, dim3(64), dim3(64), 0, stream,
                       crf_start, crf_end, crf_trans, ws, out);
}